// Round 5
// baseline (109.801 us; speedup 1.0000x reference)
//
#include <hip/hip_runtime.h>
#include <math.h>

#define MIX_RADIUS 10
#define KSIZE 21           // 2*MIX_RADIUS + 1
#define BB 4
#define SS 128
#define HW4 4096           // H*W/4 = 128*128/4 float4 columns per s-plane
#define TS 8               // outputs per thread along s
#define NPLANES (TS + 2 * MIX_RADIUS)  // 28 input planes per thread
#define TPB 256

typedef float f32x4 __attribute__((ext_vector_type(4)));

// CALIBRATION ROUND: kernel body identical to Round 4 (85.66 us). kernel_launch
// fires it 3x (idempotent: pure function of inputs, full d_out overwrite) so
//   t_kernel = (dur_us - 85.66) / 2
// decides whether the kernel is at its ~10.6 us HBM floor or has ~4 us headroom.
__global__ __launch_bounds__(TPB, 4) void adaptive_mixing_kernel(
    const float* __restrict__ x,
    const float* __restrict__ ada_mask,
    float* __restrict__ out)
{
    __shared__ float sw[TS][KSIZE];

    const int tid = threadIdx.x;
    const int b   = blockIdx.z;
    const int s0  = blockIdx.y * TS;
    const int hw4 = blockIdx.x * TPB + tid;

    // --- per-row softmax for this block's TS rows (threads 0..TS-1) ---
    if (tid < TS) {
        const float* m = ada_mask + ((long)(b * SS + (s0 + tid))) * KSIZE;
        float v[KSIZE];
        float mx = -1e30f;
        #pragma unroll
        for (int k = 0; k < KSIZE; ++k) { v[k] = m[k]; mx = fmaxf(mx, v[k]); }
        float sum = 0.f;
        #pragma unroll
        for (int k = 0; k < KSIZE; ++k) { v[k] = __expf(v[k] - mx); sum += v[k]; }
        const float inv = 1.f / sum;
        #pragma unroll
        for (int k = 0; k < KSIZE; ++k) sw[tid][k] = v[k] * inv;
    }
    __syncthreads();

    const f32x4* x4   = (const f32x4*)x;
    f32x4*       out4 = (f32x4*)out;
    const long base = (long)b * SS * HW4 + hw4;

    // --- issue ALL 28 plane loads up front (indices static after unroll) ---
    f32x4 win[NPLANES];
    #pragma unroll
    for (int i = 0; i < NPLANES; ++i) {
        const int sg = s0 - MIX_RADIUS + i;          // s0-10 .. s0+17
        win[i] = (sg >= 0 && sg < SS) ? x4[base + (long)sg * HW4]
                                      : (f32x4)(0.f);
    }

    // --- 8 outputs, 84 FMAs each ---
    #pragma unroll
    for (int j = 0; j < TS; ++j) {
        f32x4 acc = (f32x4)(0.f);
        #pragma unroll
        for (int k = 0; k < KSIZE; ++k) {
            const float wgt = sw[j][k];   // wave-uniform LDS broadcast
            acc += wgt * win[j + k];      // x(s0+j-10+k)
        }
        // write-once output: nontemporal store keeps L2/L3 for x halo reuse
        __builtin_nontemporal_store(acc, &out4[base + (long)(s0 + j) * HW4]);
    }
}

extern "C" void kernel_launch(void* const* d_in, const int* in_sizes, int n_in,
                              void* d_out, int out_size, void* d_ws, size_t ws_size,
                              hipStream_t stream) {
    const float* x    = (const float*)d_in[0];
    const float* mask = (const float*)d_in[1];
    float*       out  = (float*)d_out;

    dim3 grid(HW4 / TPB, SS / TS, BB);  // (16, 16, 4) = 1024 blocks

    // 3x launch: calibration probe. Extra dur_us over Round 4 = 2 * t_kernel.
    adaptive_mixing_kernel<<<grid, TPB, 0, stream>>>(x, mask, out);
    adaptive_mixing_kernel<<<grid, TPB, 0, stream>>>(x, mask, out);
    adaptive_mixing_kernel<<<grid, TPB, 0, stream>>>(x, mask, out);
}

// Round 6
// 83.717 us; speedup vs baseline: 1.3116x; 1.3116x over previous
//
#include <hip/hip_runtime.h>
#include <math.h>

#define MIX_RADIUS 10
#define KSIZE 21           // 2*MIX_RADIUS + 1
#define BB 4
#define SS 128
#define HW4 4096           // H*W/4 = 128*128/4 float4 columns per s-plane
#define TS 8               // outputs per thread along s
#define NPLANES (TS + 2 * MIX_RADIUS)  // 28 input planes per thread
#define TPB 256

typedef float f32x4 __attribute__((ext_vector_type(4)));

// FINAL (Round 4 structure, single launch). Calibration (R5, 3x launch):
// kernel-proper = 12.07 us = 5.56 TB/s effective on 67.1 MB compulsory HBM
// = 88% of the 6.3 TB/s achievable ceiling (measured on pure-write fills;
// mixed R/W streams sit lower). Remaining dur_us is ~73.6 us of harness
// envelope (268 MB poison fills at ~43 us dominate the profile top-5).
//
// Structure: preload ALL 28 x-planes per thread (28 KB/wave in flight ->
// HBM saturation by Little's law; beat circular-window variants by ~1.6 us),
// then 8 outputs x 84 v_fma_f32, nontemporal dwordx4 stores to keep L2/L3
// for the x halo (halo re-reads are cache-absorbed: x = 33.5 MB << 256 MB L3).
// 112 VGPR window fits the <=128-VGPR tier -> 16 waves/CU via
// __launch_bounds__(256,4).
__global__ __launch_bounds__(TPB, 4) void adaptive_mixing_kernel(
    const float* __restrict__ x,
    const float* __restrict__ ada_mask,
    float* __restrict__ out)
{
    __shared__ float sw[TS][KSIZE];

    const int tid = threadIdx.x;
    const int b   = blockIdx.z;
    const int s0  = blockIdx.y * TS;
    const int hw4 = blockIdx.x * TPB + tid;

    // --- per-row softmax for this block's TS rows (threads 0..TS-1) ---
    if (tid < TS) {
        const float* m = ada_mask + ((long)(b * SS + (s0 + tid))) * KSIZE;
        float v[KSIZE];
        float mx = -1e30f;
        #pragma unroll
        for (int k = 0; k < KSIZE; ++k) { v[k] = m[k]; mx = fmaxf(mx, v[k]); }
        float sum = 0.f;
        #pragma unroll
        for (int k = 0; k < KSIZE; ++k) { v[k] = __expf(v[k] - mx); sum += v[k]; }
        const float inv = 1.f / sum;
        #pragma unroll
        for (int k = 0; k < KSIZE; ++k) sw[tid][k] = v[k] * inv;
    }
    __syncthreads();

    const f32x4* x4   = (const f32x4*)x;
    f32x4*       out4 = (f32x4*)out;
    const long base = (long)b * SS * HW4 + hw4;

    // --- issue ALL 28 plane loads up front (indices static after unroll) ---
    f32x4 win[NPLANES];
    #pragma unroll
    for (int i = 0; i < NPLANES; ++i) {
        const int sg = s0 - MIX_RADIUS + i;          // s0-10 .. s0+17
        win[i] = (sg >= 0 && sg < SS) ? x4[base + (long)sg * HW4]
                                      : (f32x4)(0.f);
    }

    // --- 8 outputs, 84 FMAs each ---
    #pragma unroll
    for (int j = 0; j < TS; ++j) {
        f32x4 acc = (f32x4)(0.f);
        #pragma unroll
        for (int k = 0; k < KSIZE; ++k) {
            const float wgt = sw[j][k];   // wave-uniform LDS broadcast
            acc += wgt * win[j + k];      // x(s0+j-10+k)
        }
        // write-once output: nontemporal store keeps L2/L3 for x halo reuse
        __builtin_nontemporal_store(acc, &out4[base + (long)(s0 + j) * HW4]);
    }
}

extern "C" void kernel_launch(void* const* d_in, const int* in_sizes, int n_in,
                              void* d_out, int out_size, void* d_ws, size_t ws_size,
                              hipStream_t stream) {
    const float* x    = (const float*)d_in[0];
    const float* mask = (const float*)d_in[1];
    float*       out  = (float*)d_out;

    dim3 grid(HW4 / TPB, SS / TS, BB);  // (16, 16, 4) = 1024 blocks
    adaptive_mixing_kernel<<<grid, TPB, 0, stream>>>(x, mask, out);
}